// Round 4
// baseline (531.359 us; speedup 1.0000x reference)
//
#include <hip/hip_runtime.h>
#include <stdint.h>

#define N_TOK 65536
#define CDIM  512
#define C3    1536
#define HEADS 8
#define DHEAD 64
#define KTOK  256
#define PGRP  256

typedef __attribute__((ext_vector_type(8))) short bf16x8;
typedef __attribute__((ext_vector_type(4))) float f32x4;
typedef __attribute__((ext_vector_type(16))) float f32x16;
typedef __attribute__((ext_vector_type(4))) unsigned u32x4;

__device__ __forceinline__ unsigned short f2bf(float f) {
  union { float f; unsigned u; } t; t.f = f;
  return (unsigned short)((t.u + 0x7fffu + ((t.u >> 16) & 1u)) >> 16);
}

__device__ __forceinline__ unsigned cvt_pk_bf16(float lo, float hi) {
  unsigned r;
  asm("v_cvt_pk_bf16_f32 %0, %1, %2" : "=v"(r) : "v"(lo), "v"(hi));
  return r;
}

// ------------- transpose + convert (f32 R x Cc -> bf16 Cc x R) -------------
__global__ __launch_bounds__(256) void transpose_cvt(const float* __restrict__ in,
                                                     unsigned short* __restrict__ out,
                                                     int R, int Cc) {
  __shared__ float tile[32][33];
  int c0 = blockIdx.x * 32, r0 = blockIdx.y * 32;
  int tx = threadIdx.x & 31, ty = threadIdx.x >> 5;  // 32 x 8
  for (int i = ty; i < 32; i += 8)
    tile[i][tx] = in[(size_t)(r0 + i) * Cc + c0 + tx];
  __syncthreads();
  for (int i = ty; i < 32; i += 8)
    out[(size_t)(c0 + i) * R + r0 + tx] = f2bf(tile[tx][i]);
}

// ---------------- 256x256 8-phase GEMM (T2+T3+T4+T5 port) ------------------
// C[m,n] = A[gather(m),:] @ Bt[n,:]^T + bias[n].
// AF32=1: A is f32, reg-staged (global f32x4 loads in P1, cvt_pk + ds_write
//         in P4) — fuses the f32->bf16 conversion into the GEMM.
// AF32=0: A is bf16, staged via global_load_lds DMA.
// BM=BN=256, BK=64, 512 threads = 8 waves (2M x 4N), LDS 128 KiB, depth-1
// ring: tile v+1 fully staged (issued P1/P2) while tile v computes; one
// vmcnt(0)+lgkmcnt(0)+barrier per tile (issue-to-drain slack >= 2 phases).
// bf[4][2] retains all B frags -> P4 has no ds_reads (24 reads/tile).
template <int OF32, int AF32>
__global__ __launch_bounds__(512, 2) void gemm256(const void* __restrict__ Ain,
                                                  const unsigned short* __restrict__ Bt,
                                                  const float* __restrict__ bias,
                                                  void* __restrict__ Cout,
                                                  const int* __restrict__ gather,
                                                  int Nn, int Kk, int nbn) {
  __shared__ __align__(16) unsigned short As[2][256 * 64];
  __shared__ __align__(16) unsigned short Bs[2][256 * 64];

  // bijective XCD swizzle (grid % 8 == 0)
  int cpx = gridDim.x >> 3;
  int wk = (blockIdx.x & 7) * cpx + (blockIdx.x >> 3);
  int bm = wk / nbn, bn = wk % nbn;
  int m0 = bm * 256, n0 = bn * 256;

  int tid = threadIdx.x;
  int wv = tid >> 6, ln = tid & 63, g = ln >> 4, c = ln & 15;
  int wr = wv >> 2, wc = wv & 3;     // 2 x 4 wave grid
  int NT = Kk >> 6;

  const char* Ab = (const char*)Ain;
  const char* Bb = (const char*)Bt;
  int lr = tid >> 3;
  int cg = (tid & 7) ^ (lr & 7);     // pre-swizzled source column-group
  unsigned aoff[2][2], boff[2][2];
#pragma unroll
  for (int h2 = 0; h2 < 2; ++h2)
#pragma unroll
    for (int j = 0; j < 2; ++j) {
      int row = h2 * 128 + j * 64 + lr;
      int ga = gather ? gather[m0 + row] : (m0 + row);
      aoff[h2][j] = (unsigned)(((size_t)ga * Kk + cg * 8) * (AF32 ? 4 : 2));
      boff[h2][j] = (unsigned)(((size_t)(n0 + row) * Kk + cg * 8) * 2);
    }

#define DMA(src, dst)                                                       \
  __builtin_amdgcn_global_load_lds(                                          \
      (const __attribute__((address_space(1))) void*)(const void*)(src),     \
      (__attribute__((address_space(3))) void*)(dst), 16, 0, 0)

#define RD_A(mi, kc) (*(const bf16x8*)&Ac[((((2 * (mi) + wr) * 16 + c) * 8 + (((kc) * 4 + g) ^ (c & 7))) * 8)])
#define RD_B(ni, kc) (*(const bf16x8*)&Bc[((((4 * (ni) + wc) * 16 + c) * 8 + (((kc) * 4 + g) ^ (c & 7))) * 8)])

  f32x4 acc[8][4];
#pragma unroll
  for (int mi = 0; mi < 8; ++mi)
#pragma unroll
    for (int ni = 0; ni < 4; ++ni)
      acc[mi][ni] = (f32x4){0.f, 0.f, 0.f, 0.f};

  // ---- prologue: stage tile 0 fully, drain, barrier ----
  {
    unsigned short* An = &As[0][0];
    unsigned short* Bn = &Bs[0][0];
    if (AF32) {
      float4 aw[2][2][2];
#pragma unroll
      for (int h2 = 0; h2 < 2; ++h2)
#pragma unroll
        for (int j = 0; j < 2; ++j) {
          const float4* src = (const float4*)(Ab + aoff[h2][j]);
          aw[h2][j][0] = src[0];
          aw[h2][j][1] = src[1];
        }
      __builtin_amdgcn_sched_barrier(0);
#pragma unroll
      for (int h2 = 0; h2 < 2; ++h2) {
        DMA(Bb + boff[h2][0], &Bn[(h2 * 1024 + wv * 64) * 8]);
        DMA(Bb + boff[h2][1], &Bn[(h2 * 1024 + 512 + wv * 64) * 8]);
      }
#pragma unroll
      for (int h2 = 0; h2 < 2; ++h2)
#pragma unroll
        for (int j = 0; j < 2; ++j) {
          u32x4 pw;
          pw[0] = cvt_pk_bf16(aw[h2][j][0].x, aw[h2][j][0].y);
          pw[1] = cvt_pk_bf16(aw[h2][j][0].z, aw[h2][j][0].w);
          pw[2] = cvt_pk_bf16(aw[h2][j][1].x, aw[h2][j][1].y);
          pw[3] = cvt_pk_bf16(aw[h2][j][1].z, aw[h2][j][1].w);
          *(bf16x8*)&An[(h2 * 1024 + j * 512 + tid) * 8] = __builtin_bit_cast(bf16x8, pw);
        }
    } else {
#pragma unroll
      for (int h2 = 0; h2 < 2; ++h2) {
        DMA(Ab + aoff[h2][0], &An[(h2 * 1024 + wv * 64) * 8]);
        DMA(Ab + aoff[h2][1], &An[(h2 * 1024 + 512 + wv * 64) * 8]);
        DMA(Bb + boff[h2][0], &Bn[(h2 * 1024 + wv * 64) * 8]);
        DMA(Bb + boff[h2][1], &Bn[(h2 * 1024 + 512 + wv * 64) * 8]);
      }
    }
    asm volatile("s_waitcnt vmcnt(0) lgkmcnt(0)" ::: "memory");
    __builtin_amdgcn_s_barrier();
  }

  bf16x8 af[4][2], bf[4][2];

#pragma unroll 1
  for (int v = 0; v < NT; ++v) {
    unsigned short* Ac = &As[v & 1][0];
    unsigned short* Bc = &Bs[v & 1][0];
    unsigned short* An = &As[(v + 1) & 1][0];
    unsigned short* Bn = &Bs[(v + 1) & 1][0];
    bool st = (v + 1 < NT);
    unsigned ka = (unsigned)(v + 1) * (AF32 ? 256u : 128u);
    unsigned kb = (unsigned)(v + 1) * 128u;
    float4 aw[2][2][2];

    // ---- P1: quadrant (0,0); issue next-tile A
#pragma unroll
    for (int i = 0; i < 4; ++i)
#pragma unroll
      for (int kc = 0; kc < 2; ++kc) af[i][kc] = RD_A(i, kc);
#pragma unroll
    for (int j = 0; j < 2; ++j)
#pragma unroll
      for (int kc = 0; kc < 2; ++kc) bf[j][kc] = RD_B(j, kc);
    if (st) {
      if (AF32) {
#pragma unroll
        for (int h2 = 0; h2 < 2; ++h2)
#pragma unroll
          for (int j = 0; j < 2; ++j) {
            const float4* src = (const float4*)(Ab + aoff[h2][j] + ka);
            aw[h2][j][0] = src[0];
            aw[h2][j][1] = src[1];
          }
        __builtin_amdgcn_sched_barrier(0);
      } else {
#pragma unroll
        for (int h2 = 0; h2 < 2; ++h2) {
          DMA(Ab + aoff[h2][0] + ka, &An[(h2 * 1024 + wv * 64) * 8]);
          DMA(Ab + aoff[h2][1] + ka, &An[(h2 * 1024 + 512 + wv * 64) * 8]);
        }
      }
    }
    __builtin_amdgcn_s_barrier();
    asm volatile("s_waitcnt lgkmcnt(0)" ::: "memory");
    __builtin_amdgcn_sched_barrier(0);
    __builtin_amdgcn_s_setprio(1);
#pragma unroll
    for (int i = 0; i < 4; ++i)
#pragma unroll
      for (int j = 0; j < 2; ++j) {
        acc[i][j] = __builtin_amdgcn_mfma_f32_16x16x32_bf16(af[i][0], bf[j][0], acc[i][j], 0, 0, 0);
        acc[i][j] = __builtin_amdgcn_mfma_f32_16x16x32_bf16(af[i][1], bf[j][1], acc[i][j], 0, 0, 0);
      }
    __builtin_amdgcn_s_setprio(0);
    __builtin_amdgcn_s_barrier();

    // ---- P2: quadrant (0,1); issue next-tile B
#pragma unroll
    for (int j = 0; j < 2; ++j)
#pragma unroll
      for (int kc = 0; kc < 2; ++kc) bf[2 + j][kc] = RD_B(2 + j, kc);
    if (st) {
#pragma unroll
      for (int h2 = 0; h2 < 2; ++h2) {
        DMA(Bb + boff[h2][0] + kb, &Bn[(h2 * 1024 + wv * 64) * 8]);
        DMA(Bb + boff[h2][1] + kb, &Bn[(h2 * 1024 + 512 + wv * 64) * 8]);
      }
    }
    __builtin_amdgcn_s_barrier();
    asm volatile("s_waitcnt lgkmcnt(0)" ::: "memory");
    __builtin_amdgcn_sched_barrier(0);
    __builtin_amdgcn_s_setprio(1);
#pragma unroll
    for (int i = 0; i < 4; ++i)
#pragma unroll
      for (int j = 0; j < 2; ++j) {
        acc[i][2 + j] = __builtin_amdgcn_mfma_f32_16x16x32_bf16(af[i][0], bf[2 + j][0], acc[i][2 + j], 0, 0, 0);
        acc[i][2 + j] = __builtin_amdgcn_mfma_f32_16x16x32_bf16(af[i][1], bf[2 + j][1], acc[i][2 + j], 0, 0, 0);
      }
    __builtin_amdgcn_s_setprio(0);
    __builtin_amdgcn_s_barrier();

    // ---- P3: quadrant (1,1) — new A frags, reuse bf[2..3]
#pragma unroll
    for (int i = 0; i < 4; ++i)
#pragma unroll
      for (int kc = 0; kc < 2; ++kc) af[i][kc] = RD_A(4 + i, kc);
    __builtin_amdgcn_s_barrier();
    asm volatile("s_waitcnt lgkmcnt(0)" ::: "memory");
    __builtin_amdgcn_sched_barrier(0);
    __builtin_amdgcn_s_setprio(1);
#pragma unroll
    for (int i = 0; i < 4; ++i)
#pragma unroll
      for (int j = 0; j < 2; ++j) {
        acc[4 + i][2 + j] = __builtin_amdgcn_mfma_f32_16x16x32_bf16(af[i][0], bf[2 + j][0], acc[4 + i][2 + j], 0, 0, 0);
        acc[4 + i][2 + j] = __builtin_amdgcn_mfma_f32_16x16x32_bf16(af[i][1], bf[2 + j][1], acc[4 + i][2 + j], 0, 0, 0);
      }
    __builtin_amdgcn_s_setprio(0);
    __builtin_amdgcn_s_barrier();

    // ---- P4: quadrant (1,0) — no ds_reads; cvt+ds_write next-tile A (AF32)
    if (st && AF32) {
#pragma unroll
      for (int h2 = 0; h2 < 2; ++h2)
#pragma unroll
        for (int j = 0; j < 2; ++j) {
          u32x4 pw;
          pw[0] = cvt_pk_bf16(aw[h2][j][0].x, aw[h2][j][0].y);
          pw[1] = cvt_pk_bf16(aw[h2][j][0].z, aw[h2][j][0].w);
          pw[2] = cvt_pk_bf16(aw[h2][j][1].x, aw[h2][j][1].y);
          pw[3] = cvt_pk_bf16(aw[h2][j][1].z, aw[h2][j][1].w);
          *(bf16x8*)&An[(h2 * 1024 + j * 512 + tid) * 8] = __builtin_bit_cast(bf16x8, pw);
        }
    }
    __builtin_amdgcn_s_barrier();
    asm volatile("s_waitcnt lgkmcnt(0)" ::: "memory");
    __builtin_amdgcn_sched_barrier(0);
    __builtin_amdgcn_s_setprio(1);
#pragma unroll
    for (int i = 0; i < 4; ++i)
#pragma unroll
      for (int j = 0; j < 2; ++j) {
        acc[4 + i][j] = __builtin_amdgcn_mfma_f32_16x16x32_bf16(af[i][0], bf[j][0], acc[4 + i][j], 0, 0, 0);
        acc[4 + i][j] = __builtin_amdgcn_mfma_f32_16x16x32_bf16(af[i][1], bf[j][1], acc[4 + i][j], 0, 0, 0);
      }
    __builtin_amdgcn_s_setprio(0);
    // depth-1 ring: everything for tile v+1 (issued >=2 phases ago) must land
    asm volatile("s_waitcnt vmcnt(0) lgkmcnt(0)" ::: "memory");
    __builtin_amdgcn_s_barrier();
  }

  // epilogue
#pragma unroll
  for (int ni = 0; ni < 4; ++ni) {
    int col = n0 + (4 * ni + wc) * 16 + c;
    float bv = bias[col];
#pragma unroll
    for (int mi = 0; mi < 8; ++mi) {
      int rowb = m0 + (2 * mi + wr) * 16 + g * 4;
#pragma unroll
      for (int rr = 0; rr < 4; ++rr) {
        float vv = acc[mi][ni][rr] + bv;
        if (OF32) ((float*)Cout)[(size_t)(rowb + rr) * Nn + col] = vv;
        else ((unsigned short*)Cout)[(size_t)(rowb + rr) * Nn + col] = f2bf(vv);
      }
    }
  }
#undef DMA
#undef RD_A
#undef RD_B
}

// ---------------- attention: one workgroup per (p, h), 32x32 MFMA ----------
// (unchanged from previous round — see comments there)
__global__ __launch_bounds__(256, 2) void attn_k(const unsigned short* __restrict__ qkv,
                                                 const int* __restrict__ order,
                                                 unsigned short* __restrict__ attnout) {
  __shared__ __align__(16) unsigned short Ks[KTOK * 64];   // [m][d], 16B-group XOR swizzle
  __shared__ __align__(16) unsigned short Vt[64 * 256];    // [d][m], XOR swizzle

  int p = blockIdx.x >> 3, h = blockIdx.x & 7;
  int tid = threadIdx.x;
  int wv = tid >> 6, ln = tid & 63;
  int lq = ln & 31;          // q-column (QK^T) / d-column (PV)
  int hl = ln >> 5;          // lane half

  const unsigned short* base = qkv + (size_t)p * KTOK * C3 + h * DHEAD;

  // --- K staging via global_load_lds DMA, swizzle via per-lane source addr --
  {
    int mlo = tid >> 3;
    int j = (tid & 7) ^ (mlo & 7);
    const unsigned short* ksrc = base + CDIM + j * 8;
#pragma unroll
    for (int i = 0; i < 8; ++i) {
      int m = i * 32 + mlo;
      __builtin_amdgcn_global_load_lds(
          (const __attribute__((address_space(1))) void*)(ksrc + (size_t)m * C3),
          (__attribute__((address_space(3))) void*)&Ks[((i << 8) + tid) * 8],
          16, 0, 0);
    }
  }
  // --- V staging: reg round-trip, transposed write ---------------------------
  {
    const unsigned short* vrow = base + 2 * CDIM + (size_t)tid * C3;
    bf16x8 vv[8];
#pragma unroll
    for (int j = 0; j < 8; ++j) vv[j] = *(const bf16x8*)(vrow + j * 8);
#pragma unroll
    for (int j = 0; j < 8; ++j)
#pragma unroll
      for (int e = 0; e < 8; ++e) {
        int d = j * 8 + e;
        Vt[d * 256 + (((tid >> 3) ^ (d & 7)) << 3) + (tid & 7)] = (unsigned short)vv[j][e];
      }
  }

  bf16x8 qfa[2][4];
  {
    const unsigned short* qr = base + (size_t)(wv * 64 + lq) * C3;
#pragma unroll
    for (int dk = 0; dk < 4; ++dk) qfa[0][dk] = *(const bf16x8*)(qr + dk * 16 + hl * 8);
  }
  __syncthreads();

#pragma unroll
  for (int t = 0; t < 2; ++t) {
    int q0 = wv * 64 + t * 32;
    int ordv[16];
#pragma unroll
    for (int r = 0; r < 16; ++r)
      ordv[r] = order[p * KTOK + q0 + (r & 3) + 8 * (r >> 2) + 4 * hl];

    // S^T = K Q^T : 8 m-tiles x 4 d-chunks
    f32x16 sa[8];
    __builtin_amdgcn_s_setprio(1);
#pragma unroll
    for (int mt = 0; mt < 8; ++mt) {
      f32x16 z;
#pragma unroll
      for (int r = 0; r < 16; ++r) z[r] = 0.f;
      int m = mt * 32 + lq;
#pragma unroll
      for (int dk = 0; dk < 4; ++dk) {
        bf16x8 kf = *(const bf16x8*)&Ks[(m * 8 + ((dk * 2 + hl) ^ (m & 7))) * 8];
        z = __builtin_amdgcn_mfma_f32_32x32x16_bf16(kf, qfa[t][dk], z, 0, 0, 0);
      }
      sa[mt] = z;
    }
    __builtin_amdgcn_s_setprio(0);

    if (t == 0) {
      const unsigned short* qr = base + (size_t)(wv * 64 + 32 + lq) * C3;
#pragma unroll
      for (int dk = 0; dk < 4; ++dk) qfa[1][dk] = *(const bf16x8*)(qr + dk * 16 + hl * 8);
    }

    // softmax over m (lane: 128 values for q = q0+lq; partner has the rest)
    float mx = sa[0][0];
#pragma unroll
    for (int mt = 0; mt < 8; ++mt)
#pragma unroll
      for (int r = 0; r < 16; ++r) mx = fmaxf(mx, sa[mt][r]);
    mx = fmaxf(mx, __shfl_xor(mx, 32, 64));
    float sum = 0.f;
#pragma unroll
    for (int mt = 0; mt < 8; ++mt)
#pragma unroll
      for (int r = 0; r < 16; ++r) {
        float e = __expf((sa[mt][r] - mx) * 0.125f);
        sa[mt][r] = e;
        sum += e;
      }
    sum += __shfl_xor(sum, 32, 64);
    float inv = 1.f / sum;

    // O = P V : per 16-m chunk, pack A-frag in-register, 2 MFMAs (dt)
    f32x16 oa[2];
#pragma unroll
    for (int r = 0; r < 16; ++r) { oa[0][r] = 0.f; oa[1][r] = 0.f; }
#pragma unroll
    for (int kt = 0; kt < 16; ++kt) {
      int mt = kt >> 1, rb = (kt & 1) * 8;
      unsigned L0 = cvt_pk_bf16(sa[mt][rb + 0] * inv, sa[mt][rb + 1] * inv);
      unsigned L1 = cvt_pk_bf16(sa[mt][rb + 2] * inv, sa[mt][rb + 3] * inv);
      unsigned H0 = cvt_pk_bf16(sa[mt][rb + 4] * inv, sa[mt][rb + 5] * inv);
      unsigned H1 = cvt_pk_bf16(sa[mt][rb + 6] * inv, sa[mt][rb + 7] * inv);
      auto s0 = __builtin_amdgcn_permlane32_swap(L0, H0, false, false);
      auto s1 = __builtin_amdgcn_permlane32_swap(L1, H1, false, false);
      u32x4 pw;
      pw[0] = s0[0]; pw[1] = s1[0]; pw[2] = s0[1]; pw[3] = s1[1];
      bf16x8 pf = __builtin_bit_cast(bf16x8, pw);
      __builtin_amdgcn_s_setprio(1);
#pragma unroll
      for (int dt = 0; dt < 2; ++dt) {
        int d = dt * 32 + lq;
        bf16x8 vf = *(const bf16x8*)&Vt[(d * 32 + ((kt * 2 + hl) ^ (d & 7))) * 8];
        oa[dt] = __builtin_amdgcn_mfma_f32_32x32x16_bf16(pf, vf, oa[dt], 0, 0, 0);
      }
      __builtin_amdgcn_s_setprio(0);
    }

    // scatter store: row = order[q], cols h*64 + {lq, lq+32}
    size_t cb = (size_t)h * DHEAD + lq;
#pragma unroll
    for (int r = 0; r < 16; ++r) {
      size_t rb2 = (size_t)ordv[r] * CDIM + cb;
      attnout[rb2] = f2bf(oa[0][r]);
      attnout[rb2 + 32] = f2bf(oa[1][r]);
    }
  }
}

extern "C" void kernel_launch(void* const* d_in, const int* in_sizes, int n_in,
                              void* d_out, int out_size, void* d_ws, size_t ws_size,
                              hipStream_t stream) {
  const float* feat  = (const float*)d_in[0];
  const int*   order = (const int*)d_in[1];
  // d_in[2] = inverse (unused: we scatter by order instead)
  const float* Wqkv  = (const float*)d_in[3];
  const float* bqkv  = (const float*)d_in[4];
  const float* Wproj = (const float*)d_in[5];
  const float* bproj = (const float*)d_in[6];
  float* out = (float*)d_out;

  // ws layout (bf16 intermediates):
  //   qkv    : N*1536  = 201.3 MB
  //   attn   : N*512   =  67.1 MB
  //   wqkvT  : 1536*512
  //   wprojT : 512*512
  char* ws = (char*)d_ws;
  unsigned short* qkv    = (unsigned short*)ws;
  unsigned short* attn   = (unsigned short*)(ws + (size_t)N_TOK * C3 * 2);
  unsigned short* wqkvT  = (unsigned short*)(ws + (size_t)N_TOK * C3 * 2 + (size_t)N_TOK * CDIM * 2);
  unsigned short* wprojT = wqkvT + C3 * CDIM;

  transpose_cvt<<<dim3(C3 / 32, CDIM / 32), 256, 0, stream>>>(Wqkv, wqkvT, CDIM, C3);
  transpose_cvt<<<dim3(CDIM / 32, CDIM / 32), 256, 0, stream>>>(Wproj, wprojT, CDIM, CDIM);

  // qkv[n,:] = feat[order[n],:] @ Wqkv + bqkv   (f32 A read + convert fused)
  gemm256<0, 1><<<(N_TOK / 256) * (C3 / 256), 512, 0, stream>>>(
      feat, wqkvT, bqkv, qkv, order, C3, CDIM, C3 / 256);

  // block-local attention, scatter back to original row order
  attn_k<<<PGRP * HEADS, 256, 0, stream>>>(qkv, order, attn);

  // out = attn @ Wproj + bproj  (f32 output)
  gemm256<1, 0><<<(N_TOK / 256) * (CDIM / 256), 512, 0, stream>>>(
      attn, wprojT, bproj, out, nullptr, CDIM, CDIM, CDIM / 256);
}

// Round 5
// 505.322 us; speedup vs baseline: 1.0515x; 1.0515x over previous
//
#include <hip/hip_runtime.h>
#include <stdint.h>

#define N_TOK 65536
#define CDIM  512
#define C3    1536
#define HEADS 8
#define DHEAD 64
#define KTOK  256
#define PGRP  256

typedef __attribute__((ext_vector_type(8))) short bf16x8;
typedef __attribute__((ext_vector_type(4))) float f32x4;
typedef __attribute__((ext_vector_type(16))) float f32x16;
typedef __attribute__((ext_vector_type(4))) unsigned u32x4;

__device__ __forceinline__ unsigned short f2bf(float f) {
  union { float f; unsigned u; } t; t.f = f;
  return (unsigned short)((t.u + 0x7fffu + ((t.u >> 16) & 1u)) >> 16);
}

__device__ __forceinline__ unsigned cvt_pk_bf16(float lo, float hi) {
  unsigned r;
  asm("v_cvt_pk_bf16_f32 %0, %1, %2" : "=v"(r) : "v"(lo), "v"(hi));
  return r;
}

// ------------- fused prep: feat cvt + both weight transposes ---------------
// One launch instead of three (saves 2 launch gaps). Block roles:
//   [0, 4096)        : feat f32 -> bf16, grid-strided (8 float4 per thread)
//   [4096, 4864)     : Wqkv  (512 x 1536) -> wqkvT  (1536 x 512) bf16
//   [4864, 5120)     : Wproj (512 x 512)  -> wprojT (512 x 512)  bf16
__global__ __launch_bounds__(256) void prep_k(const float* __restrict__ feat,
                                              unsigned short* __restrict__ featb,
                                              const float* __restrict__ Wqkv,
                                              unsigned short* __restrict__ wqkvT,
                                              const float* __restrict__ Wproj,
                                              unsigned short* __restrict__ wprojT) {
  __shared__ float tile[32][33];
  int bid = blockIdx.x;
  if (bid < 4096) {
    size_t stride = (size_t)4096 * 256 * 4;
    size_t base = ((size_t)bid * 256 + threadIdx.x) * 4;
#pragma unroll
    for (int it = 0; it < 8; ++it) {
      size_t i = base + (size_t)it * stride;
      float4 v = *(const float4*)(feat + i);
      ushort4 o;
      o.x = f2bf(v.x); o.y = f2bf(v.y); o.z = f2bf(v.z); o.w = f2bf(v.w);
      *(ushort4*)(featb + i) = o;
    }
  } else {
    const float* in; unsigned short* out; int Cc, bx, by;
    if (bid < 4096 + 768) {
      int r = bid - 4096; in = Wqkv; out = wqkvT; Cc = C3; bx = r % 48; by = r / 48;
    } else {
      int r = bid - (4096 + 768); in = Wproj; out = wprojT; Cc = CDIM; bx = r % 16; by = r / 16;
    }
    int c0 = bx * 32, r0 = by * 32;
    int tx = threadIdx.x & 31, ty = threadIdx.x >> 5;  // 32 x 8
    for (int i = ty; i < 32; i += 8)
      tile[i][tx] = in[(size_t)(r0 + i) * Cc + c0 + tx];
    __syncthreads();
    for (int i = ty; i < 32; i += 8)
      out[(size_t)(c0 + i) * CDIM + r0 + tx] = f2bf(tile[tx][i]);
  }
}

// ---------------- 256x256 8-phase GEMM (T2+T3+T4+T5 port) ------------------
// C[m,n] = A[gather(m),:] @ Bt[n,:]^T + bias[n].  A, Bt bf16; output bf16/f32.
// BM=BN=256, BK=64, 512 threads = 8 waves (2M x 4N), LDS 128 KiB (2-slot ring).
// Interleaved frag ownership: wave wr owns m-tiles {2*mi+wr}, wave wc owns
// n-tiles {4*ni+wc} -> quadrant (mh,nh) touches exactly one A-half/B-half for
// ALL waves, so halves free up mid-tile and can be restaged 2-ahead.
// Per tile v (4 phases, quadrant order (0,0),(0,1),(1,1),(1,0)):
//   P1: read A(mh0)+B(nh0); stage A-hi(v+1)   [slot^1, fully read last tile]
//   P2: read B(nh1), reuse A; stage B-lo(v+1) [slot^1, read at prev P1/P4]
//   P3: read A(mh1), reuse B; stage A-lo(v+2) [same slot, A-lo only read @P1]
//   P4: read B(nh0);          stage B-hi(v+2) [same slot, B-hi only read @P2]
//   end P4: vmcnt(4) -> everything except the 2 newest half-tiles landed,
//   i.e. tile v+1 is fully in LDS; never drain to 0 in steady state (T4).
// PROVEN at R3 (151 us gemm1); R4's depth-1 + fused-cvt variant regressed
// (221 us) -> reverted. Do not collapse the stagger without an isolating A/B.
template <int OF32>
__global__ __launch_bounds__(512, 2) void gemm256(const unsigned short* __restrict__ A,
                                                  const unsigned short* __restrict__ Bt,
                                                  const float* __restrict__ bias,
                                                  void* __restrict__ Cout,
                                                  const int* __restrict__ gather,
                                                  int Nn, int Kk, int nbn) {
  __shared__ __align__(16) unsigned short As[2][256 * 64];
  __shared__ __align__(16) unsigned short Bs[2][256 * 64];

  // bijective XCD swizzle (grid % 8 == 0)
  int cpx = gridDim.x >> 3;
  int wk = (blockIdx.x & 7) * cpx + (blockIdx.x >> 3);
  int bm = wk / nbn, bn = wk % nbn;
  int m0 = bm * 256, n0 = bn * 256;

  int tid = threadIdx.x;
  int wv = tid >> 6, ln = tid & 63, g = ln >> 4, c = ln & 15;
  int wr = wv >> 2, wc = wv & 3;     // 2 x 4 wave grid
  int NT = Kk >> 6;

  const char* Ab = (const char*)A;
  const char* Bb = (const char*)Bt;
  int lr = tid >> 3;
  int cg = (tid & 7) ^ (lr & 7);     // pre-swizzled source column-group
  unsigned aoff[2][2], boff[2][2];
#pragma unroll
  for (int h2 = 0; h2 < 2; ++h2)
#pragma unroll
    for (int j = 0; j < 2; ++j) {
      int row = h2 * 128 + j * 64 + lr;
      int ga = gather ? gather[m0 + row] : (m0 + row);
      aoff[h2][j] = (unsigned)(((size_t)ga * Kk + cg * 8) * 2);
      boff[h2][j] = (unsigned)(((size_t)(n0 + row) * Kk + cg * 8) * 2);
    }

#define STAGE_A(t, h2) do { int _s = (t) & 1; unsigned _k = (unsigned)(t) * 128u;             \
    __builtin_amdgcn_global_load_lds(                                                          \
        (__attribute__((address_space(1))) void*)(void*)(Ab + aoff[h2][0] + _k),               \
        (__attribute__((address_space(3))) void*)&As[_s][((h2) * 1024 + wv * 64) * 8],         \
        16, 0, 0);                                                                             \
    __builtin_amdgcn_global_load_lds(                                                          \
        (__attribute__((address_space(1))) void*)(void*)(Ab + aoff[h2][1] + _k),               \
        (__attribute__((address_space(3))) void*)&As[_s][((h2) * 1024 + 512 + wv * 64) * 8],   \
        16, 0, 0);                                                                             \
  } while (0)
#define STAGE_B(t, h2) do { int _s = (t) & 1; unsigned _k = (unsigned)(t) * 128u;             \
    __builtin_amdgcn_global_load_lds(                                                          \
        (__attribute__((address_space(1))) void*)(void*)(Bb + boff[h2][0] + _k),               \
        (__attribute__((address_space(3))) void*)&Bs[_s][((h2) * 1024 + wv * 64) * 8],         \
        16, 0, 0);                                                                             \
    __builtin_amdgcn_global_load_lds(                                                          \
        (__attribute__((address_space(1))) void*)(void*)(Bb + boff[h2][1] + _k),               \
        (__attribute__((address_space(3))) void*)&Bs[_s][((h2) * 1024 + 512 + wv * 64) * 8],   \
        16, 0, 0);                                                                             \
  } while (0)
#define RD_A(mi, kc) (*(const bf16x8*)&Ac[((((2 * (mi) + wr) * 16 + c) * 8 + (((kc) * 4 + g) ^ (c & 7))) * 8)])
#define RD_B(ni, kc) (*(const bf16x8*)&Bc[((((4 * (ni) + wc) * 16 + c) * 8 + (((kc) * 4 + g) ^ (c & 7))) * 8)])

  f32x4 acc[8][4];
#pragma unroll
  for (int mi = 0; mi < 8; ++mi)
#pragma unroll
    for (int ni = 0; ni < 4; ++ni)
      acc[mi][ni] = (f32x4){0.f, 0.f, 0.f, 0.f};

  STAGE_A(0, 0); STAGE_A(0, 1); STAGE_B(0, 0); STAGE_B(0, 1);
  STAGE_A(1, 0); STAGE_A(1, 1); STAGE_B(1, 0); STAGE_B(1, 1);
  asm volatile("s_waitcnt vmcnt(8)" ::: "memory");
  __builtin_amdgcn_s_barrier();

  bf16x8 af[4][2], bf[2][2];

#pragma unroll 1
  for (int v = 0; v < NT; ++v) {
    unsigned short* Ac = &As[v & 1][0];
    unsigned short* Bc = &Bs[v & 1][0];

    // ---- P1: quadrant (0,0)
#pragma unroll
    for (int i = 0; i < 4; ++i)
#pragma unroll
      for (int kc = 0; kc < 2; ++kc) af[i][kc] = RD_A(i, kc);
#pragma unroll
    for (int j = 0; j < 2; ++j)
#pragma unroll
      for (int kc = 0; kc < 2; ++kc) bf[j][kc] = RD_B(j, kc);
    if (v >= 1 && v + 1 < NT) STAGE_A(v + 1, 1);
    __builtin_amdgcn_s_barrier();
    asm volatile("s_waitcnt lgkmcnt(0)" ::: "memory");
    __builtin_amdgcn_sched_barrier(0);
    __builtin_amdgcn_s_setprio(1);
#pragma unroll
    for (int i = 0; i < 4; ++i)
#pragma unroll
      for (int j = 0; j < 2; ++j) {
        acc[i][j] = __builtin_amdgcn_mfma_f32_16x16x32_bf16(af[i][0], bf[j][0], acc[i][j], 0, 0, 0);
        acc[i][j] = __builtin_amdgcn_mfma_f32_16x16x32_bf16(af[i][1], bf[j][1], acc[i][j], 0, 0, 0);
      }
    __builtin_amdgcn_s_setprio(0);
    __builtin_amdgcn_s_barrier();

    // ---- P2: quadrant (0,1) — reuse A frags
#pragma unroll
    for (int j = 0; j < 2; ++j)
#pragma unroll
      for (int kc = 0; kc < 2; ++kc) bf[j][kc] = RD_B(2 + j, kc);
    if (v >= 1 && v + 1 < NT) STAGE_B(v + 1, 0);
    __builtin_amdgcn_s_barrier();
    asm volatile("s_waitcnt lgkmcnt(0)" ::: "memory");
    __builtin_amdgcn_sched_barrier(0);
    __builtin_amdgcn_s_setprio(1);
#pragma unroll
    for (int i = 0; i < 4; ++i)
#pragma unroll
      for (int j = 0; j < 2; ++j) {
        acc[i][2 + j] = __builtin_amdgcn_mfma_f32_16x16x32_bf16(af[i][0], bf[j][0], acc[i][2 + j], 0, 0, 0);
        acc[i][2 + j] = __builtin_amdgcn_mfma_f32_16x16x32_bf16(af[i][1], bf[j][1], acc[i][2 + j], 0, 0, 0);
      }
    __builtin_amdgcn_s_setprio(0);
    __builtin_amdgcn_s_barrier();

    // ---- P3: quadrant (1,1) — reuse B frags
#pragma unroll
    for (int i = 0; i < 4; ++i)
#pragma unroll
      for (int kc = 0; kc < 2; ++kc) af[i][kc] = RD_A(4 + i, kc);
    if (v + 2 < NT) STAGE_A(v + 2, 0);
    __builtin_amdgcn_s_barrier();
    asm volatile("s_waitcnt lgkmcnt(0)" ::: "memory");
    __builtin_amdgcn_sched_barrier(0);
    __builtin_amdgcn_s_setprio(1);
#pragma unroll
    for (int i = 0; i < 4; ++i)
#pragma unroll
      for (int j = 0; j < 2; ++j) {
        acc[4 + i][2 + j] = __builtin_amdgcn_mfma_f32_16x16x32_bf16(af[i][0], bf[j][0], acc[4 + i][2 + j], 0, 0, 0);
        acc[4 + i][2 + j] = __builtin_amdgcn_mfma_f32_16x16x32_bf16(af[i][1], bf[j][1], acc[4 + i][2 + j], 0, 0, 0);
      }
    __builtin_amdgcn_s_setprio(0);
    __builtin_amdgcn_s_barrier();

    // ---- P4: quadrant (1,0) — reuse A frags, re-read B(nh0)
#pragma unroll
    for (int j = 0; j < 2; ++j)
#pragma unroll
      for (int kc = 0; kc < 2; ++kc) bf[j][kc] = RD_B(j, kc);
    if (v + 2 < NT) STAGE_B(v + 2, 1);
    __builtin_amdgcn_s_barrier();
    asm volatile("s_waitcnt lgkmcnt(0)" ::: "memory");
    __builtin_amdgcn_sched_barrier(0);
    __builtin_amdgcn_s_setprio(1);
#pragma unroll
    for (int i = 0; i < 4; ++i)
#pragma unroll
      for (int j = 0; j < 2; ++j) {
        acc[4 + i][j] = __builtin_amdgcn_mfma_f32_16x16x32_bf16(af[i][0], bf[j][0], acc[4 + i][j], 0, 0, 0);
        acc[4 + i][j] = __builtin_amdgcn_mfma_f32_16x16x32_bf16(af[i][1], bf[j][1], acc[4 + i][j], 0, 0, 0);
      }
    __builtin_amdgcn_s_setprio(0);
    // counted vmcnt (T4): tile v+1 fully landed; 2 newest half-tiles in flight
    if (v + 2 < NT) asm volatile("s_waitcnt vmcnt(4)" ::: "memory");
    else            asm volatile("s_waitcnt vmcnt(0)" ::: "memory");
    __builtin_amdgcn_s_barrier();
  }

  // epilogue
#pragma unroll
  for (int ni = 0; ni < 4; ++ni) {
    int col = n0 + (4 * ni + wc) * 16 + c;
    float bv = bias[col];
#pragma unroll
    for (int mi = 0; mi < 8; ++mi) {
      int rowb = m0 + (2 * mi + wr) * 16 + g * 4;
#pragma unroll
      for (int rr = 0; rr < 4; ++rr) {
        float vv = acc[mi][ni][rr] + bv;
        if (OF32) ((float*)Cout)[(size_t)(rowb + rr) * Nn + col] = vv;
        else ((unsigned short*)Cout)[(size_t)(rowb + rr) * Nn + col] = f2bf(vv);
      }
    }
  }
#undef STAGE_A
#undef STAGE_B
#undef RD_A
#undef RD_B
}

// ---------------- attention: one workgroup per (p, h), 32x32 MFMA ----------
// m214-style: swapped QK^T (mfma(K,Q)) so lane l holds scores[q = q0+(l&31)]
// for 128 of 256 m (partner lane l^32 holds the rest). Softmax fully
// in-register (in-lane reduce + one shfl_xor(32)). P -> A-frag via
// v_cvt_pk_bf16_f32 + permlane32_swap (no P LDS round-trip).
// LDS = Ks 32K + Vt 32K = 64 KB -> 2 blocks/CU. No barriers in the t-loop.
__global__ __launch_bounds__(256, 2) void attn_k(const unsigned short* __restrict__ qkv,
                                                 const int* __restrict__ order,
                                                 unsigned short* __restrict__ attnout) {
  __shared__ __align__(16) unsigned short Ks[KTOK * 64];   // [m][d], 16B-group XOR swizzle
  __shared__ __align__(16) unsigned short Vt[64 * 256];    // [d][m], XOR swizzle

  int p = blockIdx.x >> 3, h = blockIdx.x & 7;
  int tid = threadIdx.x;
  int wv = tid >> 6, ln = tid & 63;
  int lq = ln & 31;          // q-column (QK^T) / d-column (PV)
  int hl = ln >> 5;          // lane half

  const unsigned short* base = qkv + (size_t)p * KTOK * C3 + h * DHEAD;

  // --- K staging via global_load_lds DMA, swizzle via per-lane source addr --
  {
    int mlo = tid >> 3;
    int j = (tid & 7) ^ (mlo & 7);
    const unsigned short* ksrc = base + CDIM + j * 8;
#pragma unroll
    for (int i = 0; i < 8; ++i) {
      int m = i * 32 + mlo;
      __builtin_amdgcn_global_load_lds(
          (const __attribute__((address_space(1))) void*)(ksrc + (size_t)m * C3),
          (__attribute__((address_space(3))) void*)&Ks[((i << 8) + tid) * 8],
          16, 0, 0);
    }
  }
  // --- V staging: reg round-trip, transposed write ---------------------------
  {
    const unsigned short* vrow = base + 2 * CDIM + (size_t)tid * C3;
    bf16x8 vv[8];
#pragma unroll
    for (int j = 0; j < 8; ++j) vv[j] = *(const bf16x8*)(vrow + j * 8);
#pragma unroll
    for (int j = 0; j < 8; ++j)
#pragma unroll
      for (int e = 0; e < 8; ++e) {
        int d = j * 8 + e;
        Vt[d * 256 + (((tid >> 3) ^ (d & 7)) << 3) + (tid & 7)] = (unsigned short)vv[j][e];
      }
  }

  bf16x8 qfa[2][4];
  {
    const unsigned short* qr = base + (size_t)(wv * 64 + lq) * C3;
#pragma unroll
    for (int dk = 0; dk < 4; ++dk) qfa[0][dk] = *(const bf16x8*)(qr + dk * 16 + hl * 8);
  }
  __syncthreads();

#pragma unroll
  for (int t = 0; t < 2; ++t) {
    int q0 = wv * 64 + t * 32;
    int ordv[16];
#pragma unroll
    for (int r = 0; r < 16; ++r)
      ordv[r] = order[p * KTOK + q0 + (r & 3) + 8 * (r >> 2) + 4 * hl];

    // S^T = K Q^T : 8 m-tiles x 4 d-chunks
    f32x16 sa[8];
    __builtin_amdgcn_s_setprio(1);
#pragma unroll
    for (int mt = 0; mt < 8; ++mt) {
      f32x16 z;
#pragma unroll
      for (int r = 0; r < 16; ++r) z[r] = 0.f;
      int m = mt * 32 + lq;
#pragma unroll
      for (int dk = 0; dk < 4; ++dk) {
        bf16x8 kf = *(const bf16x8*)&Ks[(m * 8 + ((dk * 2 + hl) ^ (m & 7))) * 8];
        z = __builtin_amdgcn_mfma_f32_32x32x16_bf16(kf, qfa[t][dk], z, 0, 0, 0);
      }
      sa[mt] = z;
    }
    __builtin_amdgcn_s_setprio(0);

    if (t == 0) {
      const unsigned short* qr = base + (size_t)(wv * 64 + 32 + lq) * C3;
#pragma unroll
      for (int dk = 0; dk < 4; ++dk) qfa[1][dk] = *(const bf16x8*)(qr + dk * 16 + hl * 8);
    }

    // softmax over m (lane: 128 values for q = q0+lq; partner has the rest)
    float mx = sa[0][0];
#pragma unroll
    for (int mt = 0; mt < 8; ++mt)
#pragma unroll
      for (int r = 0; r < 16; ++r) mx = fmaxf(mx, sa[mt][r]);
    mx = fmaxf(mx, __shfl_xor(mx, 32, 64));
    float sum = 0.f;
#pragma unroll
    for (int mt = 0; mt < 8; ++mt)
#pragma unroll
      for (int r = 0; r < 16; ++r) {
        float e = __expf((sa[mt][r] - mx) * 0.125f);
        sa[mt][r] = e;
        sum += e;
      }
    sum += __shfl_xor(sum, 32, 64);
    float inv = 1.f / sum;

    // O = P V : per 16-m chunk, pack A-frag in-register, 2 MFMAs (dt)
    f32x16 oa[2];
#pragma unroll
    for (int r = 0; r < 16; ++r) { oa[0][r] = 0.f; oa[1][r] = 0.f; }
#pragma unroll
    for (int kt = 0; kt < 16; ++kt) {
      int mt = kt >> 1, rb = (kt & 1) * 8;
      unsigned L0 = cvt_pk_bf16(sa[mt][rb + 0] * inv, sa[mt][rb + 1] * inv);
      unsigned L1 = cvt_pk_bf16(sa[mt][rb + 2] * inv, sa[mt][rb + 3] * inv);
      unsigned H0 = cvt_pk_bf16(sa[mt][rb + 4] * inv, sa[mt][rb + 5] * inv);
      unsigned H1 = cvt_pk_bf16(sa[mt][rb + 6] * inv, sa[mt][rb + 7] * inv);
      auto s0 = __builtin_amdgcn_permlane32_swap(L0, H0, false, false);
      auto s1 = __builtin_amdgcn_permlane32_swap(L1, H1, false, false);
      u32x4 pw;
      pw[0] = s0[0]; pw[1] = s1[0]; pw[2] = s0[1]; pw[3] = s1[1];
      bf16x8 pf = __builtin_bit_cast(bf16x8, pw);
      __builtin_amdgcn_s_setprio(1);
#pragma unroll
      for (int dt = 0; dt < 2; ++dt) {
        int d = dt * 32 + lq;
        bf16x8 vf = *(const bf16x8*)&Vt[(d * 32 + ((kt * 2 + hl) ^ (d & 7))) * 8];
        oa[dt] = __builtin_amdgcn_mfma_f32_32x32x16_bf16(pf, vf, oa[dt], 0, 0, 0);
      }
      __builtin_amdgcn_s_setprio(0);
    }

    // scatter store: row = order[q], cols h*64 + {lq, lq+32}
    size_t cb = (size_t)h * DHEAD + lq;
#pragma unroll
    for (int r = 0; r < 16; ++r) {
      size_t rb2 = (size_t)ordv[r] * CDIM + cb;
      attnout[rb2] = f2bf(oa[0][r]);
      attnout[rb2 + 32] = f2bf(oa[1][r]);
    }
  }
}

extern "C" void kernel_launch(void* const* d_in, const int* in_sizes, int n_in,
                              void* d_out, int out_size, void* d_ws, size_t ws_size,
                              hipStream_t stream) {
  const float* feat  = (const float*)d_in[0];
  const int*   order = (const int*)d_in[1];
  // d_in[2] = inverse (unused: we scatter by order instead)
  const float* Wqkv  = (const float*)d_in[3];
  const float* bqkv  = (const float*)d_in[4];
  const float* Wproj = (const float*)d_in[5];
  const float* bproj = (const float*)d_in[6];
  float* out = (float*)d_out;

  // ws layout (bf16 intermediates):
  //   qkv    : N*1536  = 201.3 MB
  //   featb  : N*512   =  67.1 MB  (dead after gemm1; aliased by attn)
  //   wqkvT  : 1536*512
  //   wprojT : 512*512
  char* ws = (char*)d_ws;
  unsigned short* qkv    = (unsigned short*)ws;
  unsigned short* featb  = (unsigned short*)(ws + (size_t)N_TOK * C3 * 2);
  unsigned short* attn   = featb;  // disjoint lifetime
  unsigned short* wqkvT  = (unsigned short*)(ws + (size_t)N_TOK * C3 * 2 + (size_t)N_TOK * CDIM * 2);
  unsigned short* wprojT = wqkvT + C3 * CDIM;

  // fused prep: feat cvt + both weight transposes (one launch)
  prep_k<<<4096 + 768 + 256, 256, 0, stream>>>(feat, featb, Wqkv, wqkvT, Wproj, wprojT);

  // qkv[n,:] = feat[order[n],:] @ Wqkv + bqkv   (permuted rows directly)
  gemm256<0><<<(N_TOK / 256) * (C3 / 256), 512, 0, stream>>>(
      featb, wqkvT, bqkv, qkv, order, C3, CDIM, C3 / 256);

  // block-local attention, scatter back to original row order
  attn_k<<<PGRP * HEADS, 256, 0, stream>>>(qkv, order, attn);

  // out = attn @ Wproj + bproj  (f32 output)
  gemm256<1><<<(N_TOK / 256) * (CDIM / 256), 512, 0, stream>>>(
      attn, wprojT, bproj, out, nullptr, CDIM, CDIM, CDIM / 256);
}